// Round 2
// baseline (19702.490 us; speedup 1.0000x reference)
//
#include <hip/hip_runtime.h>
#include <math.h>

// Problem constants (from reference setup_inputs)
static constexpr int B_ = 32;
static constexpr int S_ = 2048;
static constexpr int E_ = 512;
static constexpr int V_ = 32000;
static constexpr float EPS_ = 1e-6f;
static constexpr int NB_ = 8;             // blocks (slots) per batch
static constexpr int COLS_ = E_ / NB_;    // 64 columns per slot

// ---------------------------------------------------------------------------
// K1: multi-block sequential scan. 256 blocks = 32 batches x 8 slots.
// Each block owns 64 output columns; its 512x64 W_dec slice lives in VGPRs
// (128 regs/thread, loaded once). Per step, blocks of a batch exchange their
// 64 zmid values through an agent-scope double-buffered zbuf + step-stamped
// flags, then each block redundantly computes the (deterministic) LayerNorm.
// blockIdx mapping: batch = idx%32, slot = idx/32 -> the 8 blocks of a batch
// share idx%8, i.e. likely the same XCD (perf heuristic only).
// ---------------------------------------------------------------------------
__global__ __launch_bounds__(256, 1) void scan_mb(
    const int* __restrict__ seq,     // (B,S)
    const float* __restrict__ emb,   // (V,E)
    const float* __restrict__ Wdec,  // (E,E) row-major
    const float* __restrict__ bdec,  // (E)
    const float* __restrict__ gamma, // (E)
    const float* __restrict__ beta,  // (E)
    float* __restrict__ zout,        // (B,E)
    float* __restrict__ zbuf,        // (B,2,E) exchange buffer (ws)
    int* __restrict__ flags)         // (B,NB) step-stamped flags (ws, zeroed)
{
    __shared__ float zin[E_];
    __shared__ float part[4][COLS_];
    __shared__ float red1[4], red2[4];

    const int bid  = blockIdx.x;
    const int b    = bid & 31;   // batch
    const int slot = bid >> 5;   // 0..7
    const int c0   = slot * COLS_;
    const int tid  = threadIdx.x;
    const int w    = tid >> 6;   // wave 0..3
    const int lane = tid & 63;
    const int g    = lane & 15;  // col group (4 cols)
    const int sub  = lane >> 4;  // row quarter within wave chunk
    const int R    = w * 128 + sub * 32;  // first row this thread covers

    // One-time: W slice into registers. wr[rr] = W[R+rr][c0+4g .. c0+4g+3]
    float4 wr[32];
    #pragma unroll
    for (int rr = 0; rr < 32; ++rr)
        wr[rr] = *(const float4*)(Wdec + (size_t)(R + rr) * E_ + c0 + 4 * g);

    const float g0  = gamma[tid];
    const float g1  = gamma[tid + 256];
    const float bt0 = beta[tid];
    const float bt1 = beta[tid + 256];
    const float bdr = bdec[c0 + (tid & (COLS_ - 1))];
    const float sqrtE = sqrtf((float)E_);
    const int* seqb = seq + (size_t)b * S_;
    float* zb = zbuf + (size_t)b * 2 * E_;
    int* fl = flags + b * NB_;

    // z_in(0) = emb[tok0] * sqrt(E)
    {
        const int tok0 = seqb[0];
        zin[tid]       = emb[(size_t)tok0 * E_ + tid] * sqrtE;
        zin[tid + 256] = emb[(size_t)tok0 * E_ + tid + 256] * sqrtE;
    }
    __syncthreads();

    for (int t = 0; t < S_; ++t) {
        const int p = t & 1;

        // --- matvec: h[c] = sum_r zin[r] * W[r][c] for own 64 cols ---
        float4 acc = make_float4(0.f, 0.f, 0.f, 0.f);
        #pragma unroll
        for (int q = 0; q < 8; ++q) {
            const float4 z4 = *(const float4*)&zin[R + 4 * q];
            acc.x = fmaf(z4.x, wr[4*q+0].x, acc.x);
            acc.y = fmaf(z4.x, wr[4*q+0].y, acc.y);
            acc.z = fmaf(z4.x, wr[4*q+0].z, acc.z);
            acc.w = fmaf(z4.x, wr[4*q+0].w, acc.w);
            acc.x = fmaf(z4.y, wr[4*q+1].x, acc.x);
            acc.y = fmaf(z4.y, wr[4*q+1].y, acc.y);
            acc.z = fmaf(z4.y, wr[4*q+1].z, acc.z);
            acc.w = fmaf(z4.y, wr[4*q+1].w, acc.w);
            acc.x = fmaf(z4.z, wr[4*q+2].x, acc.x);
            acc.y = fmaf(z4.z, wr[4*q+2].y, acc.y);
            acc.z = fmaf(z4.z, wr[4*q+2].z, acc.z);
            acc.w = fmaf(z4.z, wr[4*q+2].w, acc.w);
            acc.x = fmaf(z4.w, wr[4*q+3].x, acc.x);
            acc.y = fmaf(z4.w, wr[4*q+3].y, acc.y);
            acc.z = fmaf(z4.w, wr[4*q+3].z, acc.z);
            acc.w = fmaf(z4.w, wr[4*q+3].w, acc.w);
        }
        // reduce over sub (lanes g, g+16, g+32, g+48)
        acc.x += __shfl_down(acc.x, 16);
        acc.y += __shfl_down(acc.y, 16);
        acc.z += __shfl_down(acc.z, 16);
        acc.w += __shfl_down(acc.w, 16);
        acc.x += __shfl_down(acc.x, 32);
        acc.y += __shfl_down(acc.y, 32);
        acc.z += __shfl_down(acc.z, 32);
        acc.w += __shfl_down(acc.w, 32);
        if (lane < 16) *(float4*)&part[w][4 * lane] = acc;
        __syncthreads();                                   // B1

        // --- publish own zmid ---
        if (tid < COLS_) {
            const float h = part[0][tid] + part[1][tid] + part[2][tid] + part[3][tid];
            const float zmid = zin[c0 + tid] + h + bdr;
            __hip_atomic_store(zb + p * E_ + c0 + tid, zmid,
                               __ATOMIC_RELAXED, __HIP_MEMORY_SCOPE_AGENT);
        }
        __syncthreads();                                   // B2 (stores drained)
        if (tid == 0) {
            __threadfence();
            __hip_atomic_store(fl + slot, t + 1,
                               __ATOMIC_RELEASE, __HIP_MEMORY_SCOPE_AGENT);
        }

        // --- prefetch next embedding row (overlaps the spin) ---
        const int tokn = seqb[(t + 1 < S_) ? (t + 1) : t];
        const float e0 = emb[(size_t)tokn * E_ + tid];
        const float e1 = emb[(size_t)tokn * E_ + tid + 256];

        // --- wait for all 8 slots ---
        if (tid < NB_) {
            while (__hip_atomic_load(fl + tid, __ATOMIC_ACQUIRE,
                                     __HIP_MEMORY_SCOPE_AGENT) < t + 1)
                __builtin_amdgcn_s_sleep(1);
        }
        __syncthreads();                                   // B3

        // --- gather full zmid ---
        const float v0 = __hip_atomic_load(zb + p * E_ + tid,
                                           __ATOMIC_RELAXED, __HIP_MEMORY_SCOPE_AGENT);
        const float v1 = __hip_atomic_load(zb + p * E_ + tid + 256,
                                           __ATOMIC_RELAXED, __HIP_MEMORY_SCOPE_AGENT);

        // --- LayerNorm (ddof=1), computed redundantly per block ---
        float s = v0 + v1;
        #pragma unroll
        for (int off = 32; off > 0; off >>= 1) s += __shfl_down(s, off);
        if (lane == 0) red1[w] = s;
        __syncthreads();                                   // B4
        const float mu = (red1[0] + red1[1] + red1[2] + red1[3]) * (1.0f / E_);
        const float d0 = v0 - mu, d1 = v1 - mu;
        float qq = d0 * d0 + d1 * d1;
        #pragma unroll
        for (int off = 32; off > 0; off >>= 1) qq += __shfl_down(qq, off);
        if (lane == 0) red2[w] = qq;
        __syncthreads();                                   // B5
        const float var = (red2[0] + red2[1] + red2[2] + red2[3]) * (1.0f / (E_ - 1));
        const float invd = 1.0f / (sqrtf(var) + EPS_);
        const float zl0 = g0 * d0 * invd + bt0;
        const float zl1 = g1 * d1 * invd + bt1;

        if (t == S_ - 1) {
            if (slot == 0) {
                zout[(size_t)b * E_ + tid]       = zl0;
                zout[(size_t)b * E_ + tid + 256] = zl1;
            }
        } else {
            zin[tid]       = fmaf(e0, sqrtE, zl0);
            zin[tid + 256] = fmaf(e1, sqrtE, zl1);
        }
        __syncthreads();                                   // B6
    }
}

// ---------------------------------------------------------------------------
// K2: logits = z @ W_voc + b_voc (unchanged from R0 — known good, ~tail cost)
// ---------------------------------------------------------------------------
__global__ __launch_bounds__(256) void logits_kernel(
    const float* __restrict__ zfin,  // (B,E)
    const float* __restrict__ Wvoc,  // (E,V)
    const float* __restrict__ bvoc,  // (V)
    float* __restrict__ y)           // (B,V)
{
    __shared__ float zl[8 * E_];
    const int tile = blockIdx.x;
    const int bg   = blockIdx.y;
    const int tid  = threadIdx.x;

    for (int k = tid; k < 8 * E_; k += 256)
        zl[k] = zfin[(size_t)bg * 8 * E_ + k];
    __syncthreads();

    const int v0 = tile * 1024 + tid * 4;
    if (v0 >= V_) return;

    float4 acc[8];
    #pragma unroll
    for (int g = 0; g < 8; ++g) acc[g] = make_float4(0.f, 0.f, 0.f, 0.f);

    const float* wp = Wvoc + v0;
    #pragma unroll 4
    for (int i = 0; i < E_; ++i) {
        const float4 w = *(const float4*)(wp + (size_t)i * V_);
        #pragma unroll
        for (int g = 0; g < 8; ++g) {
            const float zi = zl[g * E_ + i];
            acc[g].x = fmaf(zi, w.x, acc[g].x);
            acc[g].y = fmaf(zi, w.y, acc[g].y);
            acc[g].z = fmaf(zi, w.z, acc[g].z);
            acc[g].w = fmaf(zi, w.w, acc[g].w);
        }
    }

    const float4 bv = *(const float4*)(bvoc + v0);
    #pragma unroll
    for (int g = 0; g < 8; ++g) {
        acc[g].x += bv.x; acc[g].y += bv.y; acc[g].z += bv.z; acc[g].w += bv.w;
        *(float4*)(y + (size_t)(bg * 8 + g) * V_ + v0) = acc[g];
    }
}

// ---------------------------------------------------------------------------
// K3: per-row log-sum-exp correction
// ---------------------------------------------------------------------------
__global__ __launch_bounds__(256) void lse_kernel(
    const float* __restrict__ y, float* __restrict__ corr)
{
    __shared__ float redm[4], redl[4];
    const int b = blockIdx.x;
    const int tid = threadIdx.x;
    const float* row = y + (size_t)b * V_;

    float m = -3.0e38f, l = 0.f;
    for (int v = tid; v < V_; v += 256) {
        const float x = row[v];
        const float nm = fmaxf(m, x);
        l = l * expf(m - nm) + expf(x - nm);
        m = nm;
    }
    #pragma unroll
    for (int off = 32; off > 0; off >>= 1) {
        const float om = __shfl_down(m, off);
        const float ol = __shfl_down(l, off);
        const float nm = fmaxf(m, om);
        l = l * expf(m - nm) + ol * expf(om - nm);
        m = nm;
    }
    const int lane = tid & 63, wv = tid >> 6;
    if (lane == 0) { redm[wv] = m; redl[wv] = l; }
    __syncthreads();
    if (tid == 0) {
        float M = redm[0], L = redl[0];
        for (int k = 1; k < 4; ++k) {
            const float nm = fmaxf(M, redm[k]);
            L = L * expf(M - nm) + redl[k] * expf(redm[k] - nm);
            M = nm;
        }
        corr[b] = M + logf(L);
    }
}

// ---------------------------------------------------------------------------
// K4: y -= corr[b] (in place)
// ---------------------------------------------------------------------------
__global__ __launch_bounds__(256) void fix_kernel(
    float* __restrict__ y, const float* __restrict__ corr)
{
    const int idx = blockIdx.x * 256 + threadIdx.x;   // float4 index
    const int o = idx * 4;
    const int b = o / V_;
    const float c = corr[b];
    float4 v = *(float4*)(y + o);
    v.x -= c; v.y -= c; v.z -= c; v.w -= c;
    *(float4*)(y + o) = v;
}

// ---------------------------------------------------------------------------
extern "C" void kernel_launch(void* const* d_in, const int* in_sizes, int n_in,
                              void* d_out, int out_size, void* d_ws, size_t ws_size,
                              hipStream_t stream)
{
    (void)in_sizes; (void)n_in; (void)out_size; (void)ws_size;
    const int*   seq  = (const int*)  d_in[1];
    const float* emb  = (const float*)d_in[2];
    const float* Wdec = (const float*)d_in[3];
    const float* bdec = (const float*)d_in[4];
    const float* gam  = (const float*)d_in[5];
    const float* bet  = (const float*)d_in[6];
    const float* Wvoc = (const float*)d_in[7];
    const float* bvoc = (const float*)d_in[8];

    float* out  = (float*)d_out;
    float* zout = out;            // B*E floats
    float* y    = out + B_ * E_;  // B*V floats

    // workspace layout
    float* zbuf  = (float*)d_ws;                       // B*2*E floats = 128 KiB
    int*   flags = (int*)((char*)d_ws + B_ * 2 * E_ * sizeof(float)); // B*NB ints
    float* corr  = (float*)((char*)flags + B_ * NB_ * sizeof(int));   // B floats

    // flags must start < 1 — zero them on-stream (graph-capture legal)
    hipMemsetAsync(flags, 0, B_ * NB_ * sizeof(int), stream);

    hipLaunchKernelGGL(scan_mb, dim3(B_ * NB_), dim3(256), 0, stream,
                       seq, emb, Wdec, bdec, gam, bet, zout, zbuf, flags);
    hipLaunchKernelGGL(logits_kernel, dim3(32, 4), dim3(256), 0, stream,
                       zout, Wvoc, bvoc, y);
    hipLaunchKernelGGL(lse_kernel, dim3(B_), dim3(256), 0, stream, y, corr);
    hipLaunchKernelGGL(fix_kernel, dim3(1000), dim3(256), 0, stream, y, corr);
}

// Round 3
// 18093.848 us; speedup vs baseline: 1.0889x; 1.0889x over previous
//
#include <hip/hip_runtime.h>
#include <math.h>

typedef float v4 __attribute__((ext_vector_type(4)));

static constexpr int B_ = 32;
static constexpr int S_ = 2048;
static constexpr int E_ = 512;
static constexpr int V_ = 32000;
static constexpr float EPS_ = 1e-6f;
static constexpr int NH_ = 4;     // blocks (column slices) per batch
static constexpr int CH_ = 128;   // columns per block

// ---------------------------------------------------------------------------
// K1: 4-blocks-per-batch scan. 128 blocks = 32 batches x 4 col-slices.
// Each block holds its 512x128 W_dec slice ENTIRELY in VGPRs (32 x float4 =
// 128 regs/thread, loaded via inline asm so the compiler cannot sink/remat
// the loads -- R1 failure mode). Per step: local matvec (~512 cyc), publish
// 128 zmid cols + (s,sq) stats via relaxed agent-scope stores, one release
// flag store, partners poll relaxed + one acquire fence, gather, redundant
// deterministic LayerNorm. No __threadfence, no per-step cache nukes.
// ---------------------------------------------------------------------------
__global__ __launch_bounds__(512, 2) void scan4(
    const int* __restrict__ seq,     // (B,S)
    const float* __restrict__ emb,   // (V,E)
    const float* __restrict__ Wdec,  // (E,E) row-major
    const float* __restrict__ bdec,  // (E)
    const float* __restrict__ gamma, // (E)
    const float* __restrict__ beta,  // (E)
    float* __restrict__ zout,        // (B,E)
    float* __restrict__ zpub,        // (B,2,E)      ws
    float* __restrict__ spub,        // (B,2,NH,2)   ws
    int* __restrict__ flags)         // (B,2,NH)     ws, zeroed
{
    __shared__ __align__(16) float zs[E_];        // current z_in
    __shared__ __align__(16) float zm[E_];        // full zmid (own + gathered)
    __shared__ __align__(16) float part[16][CH_]; // matvec partials
    __shared__ float sred[2][2];
    __shared__ float sarr[8];
    __shared__ int   seq_l[S_];

    const int bid  = blockIdx.x;
    const int b    = bid & 31;   // batch
    const int h    = bid >> 5;   // col-slice 0..3 (partners differ by 32 -> same XCD heuristic)
    const int c0   = h * CH_;
    const int tid  = threadIdx.x;
    const int rc   = tid >> 5;   // row chunk 0..15 (32 rows each)
    const int cg   = tid & 31;   // col group (4 cols)
    const int lane = tid & 63;
    const int wv   = tid >> 6;

    // --- W slice into VGPRs, opaque to the optimizer ---
    v4 w[32];
    {
        const float* wp = Wdec + (size_t)(rc * 32) * E_ + c0 + 4 * cg;
        #pragma unroll
        for (int q = 0; q < 32; ++q) {
            const float* p = wp + (size_t)q * E_;
            asm volatile("global_load_dwordx4 %0, %1, off\n\ts_waitcnt vmcnt(0)"
                         : "=v"(w[q]) : "v"(p));
        }
    }

    const int* seqb = seq + (size_t)b * S_;
    for (int i = tid; i < S_; i += 512) seq_l[i] = seqb[i];

    const float gmm = gamma[tid];
    const float btt = beta[tid];
    const float bdr = (tid < CH_) ? bdec[c0 + tid] : 0.f;
    const float sqrtE = sqrtf(512.0f);

    float* zpb = zpub + (size_t)b * 2 * E_;
    float* spb = spub + (size_t)b * 2 * NH_ * 2;
    int*   flg = flags + b * 2 * NH_;

    __syncthreads();
    zs[tid] = emb[(size_t)seq_l[0] * E_ + tid] * sqrtE;   // z_in(0)
    __syncthreads();

    for (int t = 0; t < S_; ++t) {
        const int p = t & 1;

        // prefetch next embedding row (consumed at step end)
        const int tn = seq_l[(t + 1 < S_) ? t + 1 : t];
        const float e = emb[(size_t)tn * E_ + tid];

        // --- matvec: own 128 cols, rows rc*32..+31 ---
        v4 acc = {0.f, 0.f, 0.f, 0.f};
        #pragma unroll
        for (int q8 = 0; q8 < 8; ++q8) {
            const v4 z4 = *(const v4*)&zs[rc * 32 + 4 * q8];
            acc += z4.x * w[4 * q8 + 0];
            acc += z4.y * w[4 * q8 + 1];
            acc += z4.z * w[4 * q8 + 2];
            acc += z4.w * w[4 * q8 + 3];
        }
        *(v4*)&part[rc][4 * cg] = acc;
        __syncthreads();                               // B1

        // --- reduce 16 row-chunks, publish zmid + local stats ---
        float s = 0.f, sq = 0.f;
        if (tid < CH_) {
            float sum = part[0][tid];
            #pragma unroll
            for (int k = 1; k < 16; ++k) sum += part[k][tid];
            const float zmid = zs[c0 + tid] + sum + bdr;
            zm[c0 + tid] = zmid;
            __hip_atomic_store(&zpb[p * E_ + c0 + tid], zmid,
                               __ATOMIC_RELAXED, __HIP_MEMORY_SCOPE_AGENT);
            s = zmid; sq = zmid * zmid;
            #pragma unroll
            for (int off = 32; off > 0; off >>= 1) {
                s  += __shfl_down(s, off);
                sq += __shfl_down(sq, off);
            }
            if (lane == 0) { sred[wv][0] = s; sred[wv][1] = sq; }
        }
        __syncthreads();                               // B1b: drains zpub stores

        if (tid == 0) {
            __hip_atomic_store(&spb[(p * NH_ + h) * 2 + 0], sred[0][0] + sred[1][0],
                               __ATOMIC_RELAXED, __HIP_MEMORY_SCOPE_AGENT);
            __hip_atomic_store(&spb[(p * NH_ + h) * 2 + 1], sred[0][1] + sred[1][1],
                               __ATOMIC_RELAXED, __HIP_MEMORY_SCOPE_AGENT);
            __hip_atomic_store(&flg[p * NH_ + h], t + 1,
                               __ATOMIC_RELEASE, __HIP_MEMORY_SCOPE_AGENT);
        }

        // --- poll the 3 partner flags (relaxed; one acquire fence after) ---
        if (tid >= 1 && tid <= 3) {
            const int hp = (h + tid) & 3;
            while (__hip_atomic_load(&flg[p * NH_ + hp], __ATOMIC_RELAXED,
                                     __HIP_MEMORY_SCOPE_AGENT) < t + 1)
                __builtin_amdgcn_s_sleep(1);
        }
        __builtin_amdgcn_fence(__ATOMIC_ACQUIRE, "agent");
        __syncthreads();                               // B2

        // --- gather partner cols + stats (sc-bit loads, straight to LLC) ---
        if (tid < 384) {
            const int hp = (h + 1 + (tid >> 7)) & 3;
            const int c  = hp * CH_ + (tid & 127);
            zm[c] = __hip_atomic_load(&zpb[p * E_ + c], __ATOMIC_RELAXED,
                                      __HIP_MEMORY_SCOPE_AGENT);
        } else if (tid >= 504) {
            const int i = tid - 504;
            sarr[i] = __hip_atomic_load(&spb[p * NH_ * 2 + i], __ATOMIC_RELAXED,
                                        __HIP_MEMORY_SCOPE_AGENT);
        }
        __syncthreads();                               // B3

        // --- LayerNorm (ddof=1), identical in all 4 blocks (fixed add order) ---
        const float St = sarr[0] + sarr[2] + sarr[4] + sarr[6];
        const float Qt = sarr[1] + sarr[3] + sarr[5] + sarr[7];
        const float mu  = St * (1.0f / E_);
        const float var = (Qt - St * mu) * (1.0f / (E_ - 1));
        const float invd = 1.0f / (sqrtf(var) + EPS_);
        const float zl = gmm * (zm[tid] - mu) * invd + btt;

        if (t == S_ - 1) {
            if (h == 0) zout[(size_t)b * E_ + tid] = zl;
        } else {
            zs[tid] = fmaf(e, sqrtE, zl);
        }
        __syncthreads();                               // B4
    }
}

// ---------------------------------------------------------------------------
// K2: y += z @ W_voc (k-split x4 for 128-block parallelism, fp32 HW atomics).
// Each block stages 32 z-rows x 128 k in LDS and reuses every W_voc float4
// across all 32 batches (1x W_voc traffic).
// ---------------------------------------------------------------------------
__global__ __launch_bounds__(256) void logits4(
    const float* __restrict__ zfin,  // (B,E)
    const float* __restrict__ Wvoc,  // (E,V)
    float* __restrict__ y)           // (B,V), pre-zeroed
{
    __shared__ float zl_s[B_][128];
    const int cb  = blockIdx.x;   // 0..31 col tiles of 1024
    const int kc  = blockIdx.y;   // 0..3  k chunks of 128
    const int tid = threadIdx.x;
    const int k0  = kc * 128;

    for (int i = tid; i < B_ * 128; i += 256) {
        const int bb = i >> 7, kk = i & 127;
        zl_s[bb][kk] = zfin[(size_t)bb * E_ + k0 + kk];
    }
    __syncthreads();

    const int v0 = cb * 1024 + tid * 4;
    if (v0 >= V_) return;

    v4 acc[B_];
    #pragma unroll
    for (int g = 0; g < B_; ++g) acc[g] = (v4){0.f, 0.f, 0.f, 0.f};

    const float* wp = Wvoc + (size_t)k0 * V_ + v0;
    for (int kk = 0; kk < 128; kk += 4) {
        const v4 w0 = *(const v4*)(wp + (size_t)(kk + 0) * V_);
        const v4 w1 = *(const v4*)(wp + (size_t)(kk + 1) * V_);
        const v4 w2 = *(const v4*)(wp + (size_t)(kk + 2) * V_);
        const v4 w3 = *(const v4*)(wp + (size_t)(kk + 3) * V_);
        #pragma unroll
        for (int g = 0; g < B_; ++g) {
            acc[g] += zl_s[g][kk + 0] * w0;
            acc[g] += zl_s[g][kk + 1] * w1;
            acc[g] += zl_s[g][kk + 2] * w2;
            acc[g] += zl_s[g][kk + 3] * w3;
        }
    }
    #pragma unroll
    for (int g = 0; g < B_; ++g) {
        float* yp = y + (size_t)g * V_ + v0;
        unsafeAtomicAdd(yp + 0, acc[g].x);
        unsafeAtomicAdd(yp + 1, acc[g].y);
        unsafeAtomicAdd(yp + 2, acc[g].z);
        unsafeAtomicAdd(yp + 3, acc[g].w);
    }
}

// ---------------------------------------------------------------------------
// K3: per-batch log-sum-exp of (y + b_voc)
// ---------------------------------------------------------------------------
__global__ __launch_bounds__(1024) void lse4(
    const float* __restrict__ y, const float* __restrict__ bvoc,
    float* __restrict__ corr)
{
    __shared__ float redm[16], redl[16];
    const int b = blockIdx.x;
    const int tid = threadIdx.x;
    const float* row = y + (size_t)b * V_;

    float m = -3.0e38f, l = 0.f;
    for (int v = tid; v < V_; v += 1024) {
        const float x = row[v] + bvoc[v];
        const float nm = fmaxf(m, x);
        l = l * __expf(m - nm) + __expf(x - nm);
        m = nm;
    }
    #pragma unroll
    for (int off = 32; off > 0; off >>= 1) {
        const float om = __shfl_down(m, off);
        const float ol = __shfl_down(l, off);
        const float nm = fmaxf(m, om);
        l = l * __expf(m - nm) + ol * __expf(om - nm);
        m = nm;
    }
    const int lane = tid & 63, wvv = tid >> 6;
    if (lane == 0) { redm[wvv] = m; redl[wvv] = l; }
    __syncthreads();
    if (tid == 0) {
        float M = redm[0], L = redl[0];
        for (int k = 1; k < 16; ++k) {
            const float nm = fmaxf(M, redm[k]);
            L = L * __expf(M - nm) + redl[k] * __expf(redm[k] - nm);
            M = nm;
        }
        corr[b] = M + logf(L);
    }
}

// ---------------------------------------------------------------------------
// K4: y = y + b_voc - corr[b]
// ---------------------------------------------------------------------------
__global__ __launch_bounds__(256) void fix4(
    float* __restrict__ y, const float* __restrict__ bvoc,
    const float* __restrict__ corr)
{
    const int idx = blockIdx.x * 256 + threadIdx.x;   // float4 index
    const size_t o = (size_t)idx * 4;
    const int b = (int)(o / V_);
    const int c = (int)(o - (size_t)b * V_);
    const float cr = corr[b];
    v4 v  = *(v4*)(y + o);
    const v4 bv = *(const v4*)(bvoc + c);
    v = v + bv;
    v = v - cr;
    *(v4*)(y + o) = v;
}

// ---------------------------------------------------------------------------
extern "C" void kernel_launch(void* const* d_in, const int* in_sizes, int n_in,
                              void* d_out, int out_size, void* d_ws, size_t ws_size,
                              hipStream_t stream)
{
    (void)in_sizes; (void)n_in; (void)out_size; (void)ws_size;
    // 0=hidden_state (unused by reference), 1=output_sequence, 2=emb_out,
    // 3=W_dec, 4=b_dec, 5=gamma, 6=beta, 7=W_voc, 8=b_voc
    const int*   seq  = (const int*)  d_in[1];
    const float* emb  = (const float*)d_in[2];
    const float* Wdec = (const float*)d_in[3];
    const float* bdec = (const float*)d_in[4];
    const float* gam  = (const float*)d_in[5];
    const float* bet  = (const float*)d_in[6];
    const float* Wvoc = (const float*)d_in[7];
    const float* bvoc = (const float*)d_in[8];

    float* out  = (float*)d_out;
    float* zout = out;            // B*E floats
    float* y    = out + B_ * E_;  // B*V floats

    // workspace layout
    float* zpub  = (float*)d_ws;                                  // B*2*E
    float* spubp = zpub + B_ * 2 * E_;                            // B*2*NH*2
    int*   flags = (int*)(spubp + B_ * 2 * NH_ * 2);              // B*2*NH
    float* corr  = (float*)(flags + B_ * 2 * NH_);                // B

    hipMemsetAsync(flags, 0, B_ * 2 * NH_ * sizeof(int), stream);
    hipMemsetAsync(y, 0, (size_t)B_ * V_ * sizeof(float), stream);

    hipLaunchKernelGGL(scan4, dim3(B_ * NH_), dim3(512), 0, stream,
                       seq, emb, Wdec, bdec, gam, bet, zout, zpub, spubp, flags);
    hipLaunchKernelGGL(logits4, dim3(32, 4), dim3(256), 0, stream, zout, Wvoc, y);
    hipLaunchKernelGGL(lse4, dim3(B_), dim3(1024), 0, stream, y, bvoc, corr);
    hipLaunchKernelGGL(fix4, dim3(1000), dim3(256), 0, stream, y, bvoc, corr);
}

// Round 4
// 5574.422 us; speedup vs baseline: 3.5344x; 3.2459x over previous
//
#include <hip/hip_runtime.h>
#include <math.h>

typedef float v4 __attribute__((ext_vector_type(4)));

static constexpr int B_ = 32;
static constexpr int S_ = 2048;
static constexpr int E_ = 512;
static constexpr int V_ = 32000;
static constexpr float EPS_ = 1e-6f;
static constexpr int NH_ = 8;     // blocks (column slices) per batch
static constexpr int CH_ = 64;    // columns per block

// ---------------------------------------------------------------------------
// K1: 8-blocks-per-batch scan. 256 blocks (1/CU) = 32 batches x 8 col-slices.
// Each block holds its 512x64 W_dec slice in VGPRs: 16 x float4 = 64 regs per
// thread (asm loads so they can't be sunk; small enough that the allocator
// has no incentive to spill -- R2's failure at 128 regs/thread).
// Cross-block exchange: RELAXED agent-scope atomics only (LLC-direct, no
// cache invalidation instructions anywhere in the loop). Ordering:
//  - zmid stores drain at the __syncthreads before the flag store (per-wave
//    s_waitcnt vmcnt(0) precedes s_barrier),
//  - tid0's stats stores are ordered before its flag store by an explicit
//    s_waitcnt vmcnt(0),
//  - consumers poll flags (relaxed) then load data (relaxed, LLC-direct);
//    control dependence + barrier prevents hoisting.
// Double-buffered by step parity; flags are monotonic step stamps.
// ---------------------------------------------------------------------------
__global__ __launch_bounds__(512, 2) void scan8(
    const int* __restrict__ seq,     // (B,S)
    const float* __restrict__ emb,   // (V,E)
    const float* __restrict__ Wdec,  // (E,E) row-major
    const float* __restrict__ bdec,  // (E)
    const float* __restrict__ gamma, // (E)
    const float* __restrict__ beta,  // (E)
    float* __restrict__ zout,        // (B,E)
    float* __restrict__ zpub,        // (B,2,E)       ws
    float* __restrict__ spub,        // (B,2,NH,2)    ws
    int* __restrict__ flags)         // (B,2,NH)      ws, zeroed
{
    __shared__ __align__(16) float zs[E_];       // z_in
    __shared__ __align__(16) float zm[E_];       // full zmid
    __shared__ __align__(16) float part[8][CH_];
    __shared__ float sl[2];
    __shared__ float sarr[2 * NH_];
    __shared__ int   seq_l[S_];

    const int bid  = blockIdx.x;
    const int b    = bid & 31;   // batch
    const int h    = bid >> 5;   // slice 0..7 (partners differ by 32 in bid -> same XCD heuristic)
    const int c0   = h * CH_;
    const int tid  = threadIdx.x;
    const int rc   = tid >> 6;   // row chunk 0..7 (64 rows)
    const int lane = tid & 63;
    const int cg   = lane & 15;  // 4-col group
    const int sub  = lane >> 4;  // 16-row subchunk
    const int row0 = rc * 64 + sub * 16;

    // --- W slice into VGPRs (16 x v4 = 64 regs), opaque to the optimizer ---
    v4 w[16];
    {
        const float* wp = Wdec + (size_t)row0 * E_ + c0 + 4 * cg;
        #pragma unroll
        for (int q = 0; q < 16; ++q) {
            const float* p = wp + (size_t)q * E_;
            asm volatile("global_load_dwordx4 %0, %1, off\n\ts_waitcnt vmcnt(0)"
                         : "=v"(w[q]) : "v"(p));
        }
    }

    const int* seqb = seq + (size_t)b * S_;
    for (int i = tid; i < S_; i += 512) seq_l[i] = seqb[i];

    const float gmm = gamma[tid];
    const float btt = beta[tid];
    const float bdr = (tid < CH_) ? bdec[c0 + tid] : 0.f;
    const float sqrtE = sqrtf(512.0f);

    float* zpb = zpub + (size_t)b * 2 * E_;
    float* spb = spub + (size_t)b * 2 * NH_ * 2;
    int*   flg = flags + b * 2 * NH_;

    __syncthreads();
    zs[tid] = emb[(size_t)seq_l[0] * E_ + tid] * sqrtE;   // z_in(0) = x_0
    __syncthreads();

    for (int t = 0; t < S_; ++t) {
        const int p = t & 1;

        // prefetch next embedding row (consumed at step end)
        const int tn = seq_l[(t + 1 < S_) ? t + 1 : t];
        const float e = emb[(size_t)tn * E_ + tid];

        // --- matvec: rows row0..row0+15, own 4 cols ---
        v4 acc = {0.f, 0.f, 0.f, 0.f};
        #pragma unroll
        for (int q = 0; q < 4; ++q) {
            const v4 z4 = *(const v4*)&zs[row0 + 4 * q];
            acc += z4.x * w[4 * q + 0];
            acc += z4.y * w[4 * q + 1];
            acc += z4.z * w[4 * q + 2];
            acc += z4.w * w[4 * q + 3];
        }
        // reduce over sub (lanes cg, cg+16, cg+32, cg+48)
        acc.x += __shfl_down(acc.x, 16);
        acc.y += __shfl_down(acc.y, 16);
        acc.z += __shfl_down(acc.z, 16);
        acc.w += __shfl_down(acc.w, 16);
        acc.x += __shfl_down(acc.x, 32);
        acc.y += __shfl_down(acc.y, 32);
        acc.z += __shfl_down(acc.z, 32);
        acc.w += __shfl_down(acc.w, 32);
        if (lane < 16) *(v4*)&part[rc][4 * cg] = acc;
        __syncthreads();                                   // B1

        // --- reduce 8 row-chunks; publish zmid + per-slice stats ---
        if (tid < CH_) {
            float sum = part[0][tid];
            #pragma unroll
            for (int k = 1; k < 8; ++k) sum += part[k][tid];
            const float zmid = zs[c0 + tid] + sum + bdr;
            zm[c0 + tid] = zmid;
            __hip_atomic_store(&zpb[p * E_ + c0 + tid], zmid,
                               __ATOMIC_RELAXED, __HIP_MEMORY_SCOPE_AGENT);
            float s = zmid, sq = zmid * zmid;
            #pragma unroll
            for (int off = 32; off > 0; off >>= 1) {
                s  += __shfl_down(s, off);
                sq += __shfl_down(sq, off);
            }
            if (tid == 0) { sl[0] = s; sl[1] = sq; }
        }
        __syncthreads();            // B2: every wave's zpub stores are drained

        if (tid == 0) {
            __hip_atomic_store(&spb[(p * NH_ + h) * 2 + 0], sl[0],
                               __ATOMIC_RELAXED, __HIP_MEMORY_SCOPE_AGENT);
            __hip_atomic_store(&spb[(p * NH_ + h) * 2 + 1], sl[1],
                               __ATOMIC_RELAXED, __HIP_MEMORY_SCOPE_AGENT);
            asm volatile("s_waitcnt vmcnt(0)" ::: "memory");   // stats before flag
            __hip_atomic_store(&flg[p * NH_ + h], t + 1,
                               __ATOMIC_RELAXED, __HIP_MEMORY_SCOPE_AGENT);
        }

        // --- poll all 8 flags (one coalesced 32B LLC load per iteration) ---
        if (tid < NH_) {
            while (__hip_atomic_load(&flg[p * NH_ + tid], __ATOMIC_RELAXED,
                                     __HIP_MEMORY_SCOPE_AGENT) < t + 1)
                __builtin_amdgcn_s_sleep(1);
        }
        __syncthreads();                                   // B3

        // --- gather 448 partner cols + 16 stats (LLC-direct loads) ---
        if (tid < 7 * CH_) {
            const int sp  = (h + 1 + (tid >> 6)) & 7;
            const int col = sp * CH_ + (tid & 63);
            zm[col] = __hip_atomic_load(&zpb[p * E_ + col], __ATOMIC_RELAXED,
                                        __HIP_MEMORY_SCOPE_AGENT);
        } else if (tid >= 496) {
            const int k = tid - 496;
            sarr[k] = __hip_atomic_load(&spb[p * NH_ * 2 + k], __ATOMIC_RELAXED,
                                        __HIP_MEMORY_SCOPE_AGENT);
        }
        __syncthreads();                                   // B4

        // --- LayerNorm (ddof=1); identical fixed-order stats in all blocks ---
        float St = 0.f, Qt = 0.f;
        #pragma unroll
        for (int k = 0; k < NH_; ++k) { St += sarr[2 * k]; Qt += sarr[2 * k + 1]; }
        const float mu   = St * (1.0f / E_);
        const float var  = (Qt - St * mu) * (1.0f / (E_ - 1));
        const float invd = 1.0f / (sqrtf(var) + EPS_);
        const float zl   = gmm * (zm[tid] - mu) * invd + btt;

        if (t == S_ - 1) {
            if (h == 0) zout[(size_t)b * E_ + tid] = zl;
        } else {
            zs[tid] = fmaf(e, sqrtE, zl);
        }
        __syncthreads();                                   // B5
    }
}

// ---------------------------------------------------------------------------
// K2: y += z @ W_voc (k-split x4, fp32 HW atomics, 32-batch W reuse)
// ---------------------------------------------------------------------------
__global__ __launch_bounds__(256) void logits4(
    const float* __restrict__ zfin,  // (B,E)
    const float* __restrict__ Wvoc,  // (E,V)
    float* __restrict__ y)           // (B,V), pre-zeroed
{
    __shared__ float zl_s[B_][128];
    const int cb  = blockIdx.x;   // 0..31 col tiles of 1024
    const int kc  = blockIdx.y;   // 0..3  k chunks of 128
    const int tid = threadIdx.x;
    const int k0  = kc * 128;

    for (int i = tid; i < B_ * 128; i += 256) {
        const int bb = i >> 7, kk = i & 127;
        zl_s[bb][kk] = zfin[(size_t)bb * E_ + k0 + kk];
    }
    __syncthreads();

    const int v0 = cb * 1024 + tid * 4;
    if (v0 >= V_) return;

    v4 acc[B_];
    #pragma unroll
    for (int g = 0; g < B_; ++g) acc[g] = (v4){0.f, 0.f, 0.f, 0.f};

    const float* wp = Wvoc + (size_t)k0 * V_ + v0;
    for (int kk = 0; kk < 128; kk += 4) {
        const v4 w0 = *(const v4*)(wp + (size_t)(kk + 0) * V_);
        const v4 w1 = *(const v4*)(wp + (size_t)(kk + 1) * V_);
        const v4 w2 = *(const v4*)(wp + (size_t)(kk + 2) * V_);
        const v4 w3 = *(const v4*)(wp + (size_t)(kk + 3) * V_);
        #pragma unroll
        for (int g = 0; g < B_; ++g) {
            acc[g] += zl_s[g][kk + 0] * w0;
            acc[g] += zl_s[g][kk + 1] * w1;
            acc[g] += zl_s[g][kk + 2] * w2;
            acc[g] += zl_s[g][kk + 3] * w3;
        }
    }
    #pragma unroll
    for (int g = 0; g < B_; ++g) {
        float* yp = y + (size_t)g * V_ + v0;
        unsafeAtomicAdd(yp + 0, acc[g].x);
        unsafeAtomicAdd(yp + 1, acc[g].y);
        unsafeAtomicAdd(yp + 2, acc[g].z);
        unsafeAtomicAdd(yp + 3, acc[g].w);
    }
}

// ---------------------------------------------------------------------------
// K3: per-batch log-sum-exp of (y + b_voc)
// ---------------------------------------------------------------------------
__global__ __launch_bounds__(1024) void lse4(
    const float* __restrict__ y, const float* __restrict__ bvoc,
    float* __restrict__ corr)
{
    __shared__ float redm[16], redl[16];
    const int b = blockIdx.x;
    const int tid = threadIdx.x;
    const float* row = y + (size_t)b * V_;

    float m = -3.0e38f, l = 0.f;
    for (int v = tid; v < V_; v += 1024) {
        const float x = row[v] + bvoc[v];
        const float nm = fmaxf(m, x);
        l = l * __expf(m - nm) + __expf(x - nm);
        m = nm;
    }
    #pragma unroll
    for (int off = 32; off > 0; off >>= 1) {
        const float om = __shfl_down(m, off);
        const float ol = __shfl_down(l, off);
        const float nm = fmaxf(m, om);
        l = l * __expf(m - nm) + ol * __expf(om - nm);
        m = nm;
    }
    const int lane = tid & 63, wvv = tid >> 6;
    if (lane == 0) { redm[wvv] = m; redl[wvv] = l; }
    __syncthreads();
    if (tid == 0) {
        float M = redm[0], L = redl[0];
        for (int k = 1; k < 16; ++k) {
            const float nm = fmaxf(M, redm[k]);
            L = L * __expf(M - nm) + redl[k] * __expf(redm[k] - nm);
            M = nm;
        }
        corr[b] = M + logf(L);
    }
}

// ---------------------------------------------------------------------------
// K4: y = y + b_voc - corr[b]
// ---------------------------------------------------------------------------
__global__ __launch_bounds__(256) void fix4(
    float* __restrict__ y, const float* __restrict__ bvoc,
    const float* __restrict__ corr)
{
    const int idx = blockIdx.x * 256 + threadIdx.x;   // float4 index
    const size_t o = (size_t)idx * 4;
    const int b = (int)(o / V_);
    const int c = (int)(o - (size_t)b * V_);
    const float cr = corr[b];
    v4 v  = *(v4*)(y + o);
    const v4 bv = *(const v4*)(bvoc + c);
    v = v + bv;
    v = v - cr;
    *(v4*)(y + o) = v;
}

// ---------------------------------------------------------------------------
extern "C" void kernel_launch(void* const* d_in, const int* in_sizes, int n_in,
                              void* d_out, int out_size, void* d_ws, size_t ws_size,
                              hipStream_t stream)
{
    (void)in_sizes; (void)n_in; (void)out_size; (void)ws_size;
    // 0=hidden_state (unused), 1=output_sequence, 2=emb_out, 3=W_dec,
    // 4=b_dec, 5=gamma, 6=beta, 7=W_voc, 8=b_voc
    const int*   seq  = (const int*)  d_in[1];
    const float* emb  = (const float*)d_in[2];
    const float* Wdec = (const float*)d_in[3];
    const float* bdec = (const float*)d_in[4];
    const float* gam  = (const float*)d_in[5];
    const float* bet  = (const float*)d_in[6];
    const float* Wvoc = (const float*)d_in[7];
    const float* bvoc = (const float*)d_in[8];

    float* out  = (float*)d_out;
    float* zout = out;            // B*E floats
    float* y    = out + B_ * E_;  // B*V floats

    // workspace layout
    float* zpub  = (float*)d_ws;                                  // B*2*E
    float* spubp = zpub + B_ * 2 * E_;                            // B*2*NH*2
    int*   flags = (int*)(spubp + B_ * 2 * NH_ * 2);              // B*2*NH
    float* corr  = (float*)(flags + B_ * 2 * NH_);                // B

    hipMemsetAsync(flags, 0, B_ * 2 * NH_ * sizeof(int), stream);
    hipMemsetAsync(y, 0, (size_t)B_ * V_ * sizeof(float), stream);

    hipLaunchKernelGGL(scan8, dim3(B_ * NH_), dim3(512), 0, stream,
                       seq, emb, Wdec, bdec, gam, bet, zout, zpub, spubp, flags);
    hipLaunchKernelGGL(logits4, dim3(32, 4), dim3(256), 0, stream, zout, Wvoc, y);
    hipLaunchKernelGGL(lse4, dim3(B_), dim3(1024), 0, stream, y, bvoc, corr);
    hipLaunchKernelGGL(fix4, dim3(1000), dim3(256), 0, stream, y, bvoc, corr);
}

// Round 5
// 4346.057 us; speedup vs baseline: 4.5334x; 1.2826x over previous
//
#include <hip/hip_runtime.h>
#include <math.h>

typedef float v4 __attribute__((ext_vector_type(4)));
typedef unsigned long long u64;

static constexpr int B_ = 32;
static constexpr int S_ = 2048;
static constexpr int E_ = 512;
static constexpr int V_ = 32000;
static constexpr float EPS_ = 1e-6f;
static constexpr int NH_ = 8;     // blocks (column slices) per batch
static constexpr int CH_ = 64;    // columns per block

// ---------------------------------------------------------------------------
// K1: 8-blocks-per-batch scan, 256 blocks x 1024 threads (1 block/CU).
// W slice 512x64 in VGPRs: 8 x v4 = 32 regs/thread (asm-pinned loads).
// Cross-block exchange: TAGGED 64-bit elements (step<<32 | value bits) via
// relaxed agent-scope atomics. No flags, no store-drain before release, no
// stats round-trip: consumers poll their own element; LN stats are computed
// locally from the gathered (bitwise-identical) 512 values in fixed order.
// Double-buffered by step parity; exact-match tag kills stale/poison reads.
// ---------------------------------------------------------------------------
__global__ __launch_bounds__(1024) void scan8w(
    const int* __restrict__ seq,     // (B,S)
    const float* __restrict__ emb,   // (V,E)
    const float* __restrict__ Wdec,  // (E,E) row-major
    const float* __restrict__ bdec,  // (E)
    const float* __restrict__ gamma, // (E)
    const float* __restrict__ beta,  // (E)
    float* __restrict__ zout,        // (B,E)
    u64* __restrict__ zpub)          // (B,2,E) tagged exchange (ws, zeroed)
{
    __shared__ __align__(16) float zs[E_];        // z_in
    __shared__ __align__(16) float part[16][CH_]; // matvec partials
    __shared__ float zmL[CH_];                    // own zmid slice
    __shared__ float sred[16][2];
    __shared__ int   seq_l[S_];

    const int bid  = blockIdx.x;
    const int b    = bid & 31;    // batch
    const int h    = bid >> 5;    // slice 0..7
    const int c0   = h * CH_;
    const int tid  = threadIdx.x;
    const int wv   = tid >> 6;    // 16 waves
    const int lane = tid & 63;
    const int cg   = lane & 15;   // 4-col group
    const int sub  = lane >> 4;   // 8-row subchunk
    const int row0 = wv * 32 + sub * 8;

    // --- W slice into VGPRs (8 x v4 = 32 regs), pinned via asm ---
    v4 w[8];
    {
        const float* wp = Wdec + (size_t)row0 * E_ + c0 + 4 * cg;
        #pragma unroll
        for (int q = 0; q < 8; ++q) {
            const float* p = wp + (size_t)q * E_;
            asm volatile("global_load_dwordx4 %0, %1, off\n\ts_waitcnt vmcnt(0)"
                         : "=v"(w[q]) : "v"(p));
        }
    }

    const int* seqb = seq + (size_t)b * S_;
    for (int i = tid; i < S_; i += 1024) seq_l[i] = seqb[i];

    const float gmm = (tid < E_) ? gamma[tid] : 0.f;
    const float btt = (tid < E_) ? beta[tid] : 0.f;
    const float bdr = (tid < CH_) ? bdec[c0 + tid] : 0.f;
    const float sqrtE = sqrtf(512.0f);
    u64* zpb = zpub + (size_t)b * 2 * E_;

    __syncthreads();
    if (tid < E_) zs[tid] = emb[(size_t)seq_l[0] * E_ + tid] * sqrtE;  // x_0
    __syncthreads();

    for (int t = 0; t < S_; ++t) {
        const int p = t & 1;
        const unsigned tag = (unsigned)(t + 1);

        // prefetch next embedding row (consumed at step end)
        const int tn = seq_l[(t + 1 < S_) ? t + 1 : t];
        float e = 0.f;
        if (tid < E_) e = emb[(size_t)tn * E_ + tid];

        // --- matvec: 8 rows x own 4 cols per thread ---
        const v4 za = *(const v4*)&zs[row0];
        const v4 zb = *(const v4*)&zs[row0 + 4];
        v4 acc = za.x * w[0];
        acc += za.y * w[1];
        acc += za.z * w[2];
        acc += za.w * w[3];
        acc += zb.x * w[4];
        acc += zb.y * w[5];
        acc += zb.z * w[6];
        acc += zb.w * w[7];
        // reduce over sub (lanes cg, cg+16, cg+32, cg+48)
        acc.x += __shfl_down(acc.x, 16);
        acc.y += __shfl_down(acc.y, 16);
        acc.z += __shfl_down(acc.z, 16);
        acc.w += __shfl_down(acc.w, 16);
        acc.x += __shfl_down(acc.x, 32);
        acc.y += __shfl_down(acc.y, 32);
        acc.z += __shfl_down(acc.z, 32);
        acc.w += __shfl_down(acc.w, 32);
        if (lane < 16) *(v4*)&part[wv][4 * cg] = acc;
        __syncthreads();                                   // B1

        // --- col-reduce + tagged publish (wave 0 only) ---
        if (tid < CH_) {
            float sum = part[0][tid];
            #pragma unroll
            for (int k = 1; k < 16; ++k) sum += part[k][tid];
            const float zmid = zs[c0 + tid] + sum + bdr;
            zmL[tid] = zmid;
            union { float f; unsigned u; } cv; cv.f = zmid;
            const u64 pk = ((u64)tag << 32) | cv.u;
            __hip_atomic_store(&zpb[p * E_ + c0 + tid], pk,
                               __ATOMIC_RELAXED, __HIP_MEMORY_SCOPE_AGENT);
        }
        __syncthreads();                                   // B2 (zmL visible)

        // --- obtain all 512 zmid values (own: LDS; partner: tagged poll) ---
        float zmv = 0.f;
        if (tid < E_) {
            if ((tid >> 6) == h) {
                zmv = zmL[tid & 63];
            } else {
                u64 v;
                do {
                    v = __hip_atomic_load(&zpb[p * E_ + tid], __ATOMIC_RELAXED,
                                          __HIP_MEMORY_SCOPE_AGENT);
                } while ((unsigned)(v >> 32) != tag);
                union { unsigned u; float f; } cv; cv.u = (unsigned)v;
                zmv = cv.f;
            }
        }

        // --- LN stats, locally, fixed order (identical in all 8 blocks) ---
        float s = zmv, q = zmv * zmv;
        #pragma unroll
        for (int off = 32; off > 0; off >>= 1) {
            s += __shfl_down(s, off);
            q += __shfl_down(q, off);
        }
        if (lane == 0) { sred[wv][0] = s; sred[wv][1] = q; }
        __syncthreads();                                   // B3

        float St = 0.f, Qt = 0.f;
        #pragma unroll
        for (int k = 0; k < 8; ++k) { St += sred[k][0]; Qt += sred[k][1]; }
        const float mu   = St * (1.0f / E_);
        const float var  = (Qt - St * mu) * (1.0f / (E_ - 1));
        const float invd = 1.0f / (sqrtf(var) + EPS_);
        const float zl   = gmm * (zmv - mu) * invd + btt;

        if (t == S_ - 1) {
            if (h == 0 && tid < E_) zout[(size_t)b * E_ + tid] = zl;
        } else if (tid < E_) {
            zs[tid] = fmaf(e, sqrtE, zl);
        }
        __syncthreads();                                   // B4
    }
}

// ---------------------------------------------------------------------------
// K2: y = z @ W_voc + b_voc. 250 blocks x 512 threads; each thread owns one
// vocab column for 8 batches (bg group). z reads are thread-uniform ->
// scalar-cache loads; W_voc streamed once (same cols across bg reuse L1).
// No atomics, bias folded, direct store.
// ---------------------------------------------------------------------------
__global__ __launch_bounds__(512) void logits_k(
    const float* __restrict__ zfin,  // (B,E)
    const float* __restrict__ Wvoc,  // (E,V)
    const float* __restrict__ bvoc,  // (V)
    float* __restrict__ y)           // (B,V)
{
    const int tid = threadIdx.x;
    const int col = blockIdx.x * 128 + (tid & 127);
    const int bg  = (tid >> 7) * 8;           // 0,8,16,24

    float acc[8] = {0.f, 0.f, 0.f, 0.f, 0.f, 0.f, 0.f, 0.f};
    const float* wp = Wvoc + col;
    const float* zp = zfin + (size_t)bg * E_;

    for (int k = 0; k < E_; k += 4) {
        const float w0 = wp[(size_t)(k + 0) * V_];
        const float w1 = wp[(size_t)(k + 1) * V_];
        const float w2 = wp[(size_t)(k + 2) * V_];
        const float w3 = wp[(size_t)(k + 3) * V_];
        #pragma unroll
        for (int g = 0; g < 8; ++g) {
            acc[g] = fmaf(zp[g * E_ + k + 0], w0, acc[g]);
            acc[g] = fmaf(zp[g * E_ + k + 1], w1, acc[g]);
            acc[g] = fmaf(zp[g * E_ + k + 2], w2, acc[g]);
            acc[g] = fmaf(zp[g * E_ + k + 3], w3, acc[g]);
        }
    }
    const float bv = bvoc[col];
    #pragma unroll
    for (int g = 0; g < 8; ++g)
        y[(size_t)(bg + g) * V_ + col] = acc[g] + bv;
}

// ---------------------------------------------------------------------------
// K3: per-batch log-sum-exp (bias already folded into y)
// ---------------------------------------------------------------------------
__global__ __launch_bounds__(1024) void lse_k(
    const float* __restrict__ y, float* __restrict__ corr)
{
    __shared__ float redm[16], redl[16];
    const int b = blockIdx.x;
    const int tid = threadIdx.x;
    const float* row = y + (size_t)b * V_;

    float m = -3.0e38f, l = 0.f;
    for (int v = tid; v < V_; v += 1024) {
        const float x = row[v];
        const float nm = fmaxf(m, x);
        l = l * __expf(m - nm) + __expf(x - nm);
        m = nm;
    }
    #pragma unroll
    for (int off = 32; off > 0; off >>= 1) {
        const float om = __shfl_down(m, off);
        const float ol = __shfl_down(l, off);
        const float nm = fmaxf(m, om);
        l = l * __expf(m - nm) + ol * __expf(om - nm);
        m = nm;
    }
    const int lane = tid & 63, wvv = tid >> 6;
    if (lane == 0) { redm[wvv] = m; redl[wvv] = l; }
    __syncthreads();
    if (tid == 0) {
        float M = redm[0], L = redl[0];
        for (int k = 1; k < 16; ++k) {
            const float nm = fmaxf(M, redm[k]);
            L = L * __expf(M - nm) + redl[k] * __expf(redm[k] - nm);
            M = nm;
        }
        corr[b] = M + logf(L);
    }
}

// ---------------------------------------------------------------------------
// K4: y -= corr[b]
// ---------------------------------------------------------------------------
__global__ __launch_bounds__(256) void fix_k(
    float* __restrict__ y, const float* __restrict__ corr)
{
    const int idx = blockIdx.x * 256 + threadIdx.x;   // float4 index
    const size_t o = (size_t)idx * 4;
    const int b = (int)(o / V_);
    const float cr = corr[b];
    v4 v = *(v4*)(y + o);
    v = v - cr;
    *(v4*)(y + o) = v;
}

// ---------------------------------------------------------------------------
extern "C" void kernel_launch(void* const* d_in, const int* in_sizes, int n_in,
                              void* d_out, int out_size, void* d_ws, size_t ws_size,
                              hipStream_t stream)
{
    (void)in_sizes; (void)n_in; (void)out_size; (void)ws_size;
    // 0=hidden_state (unused), 1=output_sequence, 2=emb_out, 3=W_dec,
    // 4=b_dec, 5=gamma, 6=beta, 7=W_voc, 8=b_voc
    const int*   seq  = (const int*)  d_in[1];
    const float* emb  = (const float*)d_in[2];
    const float* Wdec = (const float*)d_in[3];
    const float* bdec = (const float*)d_in[4];
    const float* gam  = (const float*)d_in[5];
    const float* bet  = (const float*)d_in[6];
    const float* Wvoc = (const float*)d_in[7];
    const float* bvoc = (const float*)d_in[8];

    float* out  = (float*)d_out;
    float* zout = out;            // B*E floats
    float* y    = out + B_ * E_;  // B*V floats

    // workspace layout
    u64*   zpub = (u64*)d_ws;                          // B*2*E u64 = 256 KiB
    float* corr = (float*)((char*)d_ws + (size_t)B_ * 2 * E_ * sizeof(u64)); // B

    // tags must not alias t+1 from a previous replay — zero the exchange buf
    hipMemsetAsync(zpub, 0, (size_t)B_ * 2 * E_ * sizeof(u64), stream);

    hipLaunchKernelGGL(scan8w, dim3(B_ * NH_), dim3(1024), 0, stream,
                       seq, emb, Wdec, bdec, gam, bet, zout, zpub);
    hipLaunchKernelGGL(logits_k, dim3(V_ / 128), dim3(512), 0, stream,
                       zout, Wvoc, bvoc, y);
    hipLaunchKernelGGL(lse_k, dim3(B_), dim3(1024), 0, stream, y, corr);
    hipLaunchKernelGGL(fix_k, dim3(1000), dim3(256), 0, stream, y, corr);
}